// Round 1
// baseline (296.903 us; speedup 1.0000x reference)
//
#include <hip/hip_runtime.h>
#include <stdint.h>

typedef __attribute__((ext_vector_type(8))) __bf16 bf16x8;
typedef __attribute__((ext_vector_type(4))) float f32x4;
typedef __attribute__((ext_vector_type(16))) float f32x16;
typedef unsigned short u16;
typedef unsigned char u8;
typedef unsigned int u32;
typedef long i64;

#define LN_EPS 1e-5f

__device__ __forceinline__ float bf2f(u16 u){
  union { u32 i; float f; } v; v.i = ((u32)u) << 16; return v.f;
}
__device__ __forceinline__ u16 f2bf(float f){
  union { float f; u32 i; } v; v.f = f;
  u32 u = v.i;
  u += 0x7fffu + ((u >> 16) & 1u);
  return (u16)(u >> 16);
}
// HW packed f32x2 -> 2x OCP e4m3 bytes (low word of dst). RNE + sat@448.
__device__ __forceinline__ u32 cvt_pk_fp8(float a, float b){
  u32 pk;
  asm("v_cvt_pk_fp8_f32 %0, %1, %2" : "=v"(pk) : "v"(a), "v"(b));
  return pk;   // byte0 = fp8(a), byte1 = fp8(b); high bytes undefined
}

// Async global->LDS DMA, 16 B per lane (dest = uniform base + lane*16).
__device__ __forceinline__ void gload_lds16(const void* g, void* l) {
  __builtin_amdgcn_global_load_lds(
      (const __attribute__((address_space(1))) void*)g,
      (__attribute__((address_space(3))) void*)l, 16, 0, 0);
}

// ---------------------------------------------------------------------------
// Kernel 0: cast X f32 -> bf16 (one shot; kills 12x redundant conversion)
// ---------------------------------------------------------------------------
__global__ void xcast_kernel(const float* __restrict__ X, u16* __restrict__ Xb) {
  int idx = (blockIdx.x * 256 + threadIdx.x) * 8;
  float4 f0 = *(const float4*)&X[idx];
  float4 f1 = *(const float4*)&X[idx + 4];
  ushort4 lo, hi;
  lo.x = f2bf(f0.x); lo.y = f2bf(f0.y); lo.z = f2bf(f0.z); lo.w = f2bf(f0.w);
  hi.x = f2bf(f1.x); hi.y = f2bf(f1.y); hi.z = f2bf(f1.z); hi.w = f2bf(f1.w);
  *(ushort4*)&Xb[idx] = lo;
  *(ushort4*)&Xb[idx + 4] = hi;
}

// ---------------------------------------------------------------------------
// Kernel 1: transpose f32 weights -> Wt[3][512][512] bf16
// ---------------------------------------------------------------------------
__global__ void transpose_w_kernel(const float* __restrict__ Wq,
                                   const float* __restrict__ Wk,
                                   const float* __restrict__ Wv,
                                   u16* __restrict__ Wt) {
  const float* W = (blockIdx.y == 0) ? Wq : ((blockIdx.y == 1) ? Wk : Wv);
  u16* o = Wt + blockIdx.y * 512 * 512;
  int idx = blockIdx.x * 256 + threadIdx.x;
  int e = idx >> 9, d = idx & 511;
  o[e * 512 + d] = f2bf(W[d * 512 + e]);
}

// ---------------------------------------------------------------------------
// Kernel 2: QKV GEMM, fully DMA-staged (global_load_lds w=16 for A and B).
// As/Bs: 128 rows x 64 B, 16B granule g of row r stored at position g^(r&3).
// Q,K out fp8; V out fp8 TRANSPOSED Vt8[512][16384].
// Epilogue uses v_cvt_pk_fp8_f32 (was ~10 VALU ops per scalar).
// ---------------------------------------------------------------------------
__launch_bounds__(256, 4)
__global__ void qkv_gemm_kernel(const u16* __restrict__ Xb,
                                const u16* __restrict__ Wt,
                                u8* __restrict__ Qo,
                                u8* __restrict__ Ko,
                                u8* __restrict__ Vto8) {
  const int z = blockIdx.y;
  const u16* Wtm = Wt + z * 512 * 512;
  const int mblk = blockIdx.x & 127;
  const int nblk = blockIdx.x >> 7;
  const int m0 = mblk * 128, n0 = nblk * 128;

  __shared__ __align__(16) u8 As[128 * 64];   // 8 KB
  __shared__ __align__(16) u8 Bs[128 * 64];   // 8 KB

  const int tid = threadIdx.x;
  const int lane = tid & 63, w = tid >> 6;
  const int wr = w >> 1, wc = w & 1;
  const int lrow = lane & 15, quad = lane >> 4;

  f32x4 acc[4][4];
#pragma unroll
  for (int i = 0; i < 4; i++)
#pragma unroll
    for (int j = 0; j < 4; j++) acc[i][j] = (f32x4){0.f, 0.f, 0.f, 0.f};

  const int srow = lane >> 2;          // 0..15 within run
  const int spos = lane & 3;           // granule position 0..3

  // preload k0 = 0
#pragma unroll
  for (int r2 = 0; r2 < 2; r2++) {
    int rowb = w * 32 + r2 * 16;
    int row = rowb + srow;
    int g = spos ^ (row & 3);
    gload_lds16(&Xb[(m0 + row) * 512 + g * 8], &As[rowb * 64]);
    gload_lds16(&Wtm[(n0 + row) * 512 + g * 8], &Bs[rowb * 64]);
  }

  for (int k = 0; k < 16; k++) {
    __syncthreads();   // tile-k DMAs complete (implicit vmcnt(0))
    bf16x8 a[4], b[4];
#pragma unroll
    for (int t = 0; t < 4; t++) {
      int ra = wr * 64 + t * 16 + lrow;
      a[t] = *(const bf16x8*)&As[ra * 64 + (quad ^ (ra & 3)) * 16];
      int rb = wc * 64 + t * 16 + lrow;
      b[t] = *(const bf16x8*)&Bs[rb * 64 + (quad ^ (rb & 3)) * 16];
    }
    __syncthreads();   // all waves' fragment reads done -> safe to restage
    if (k < 15) {
      int k0n = (k + 1) * 32;
#pragma unroll
      for (int r2 = 0; r2 < 2; r2++) {
        int rowb = w * 32 + r2 * 16;
        int row = rowb + srow;
        int g = spos ^ (row & 3);
        gload_lds16(&Xb[(m0 + row) * 512 + k0n + g * 8], &As[rowb * 64]);
        gload_lds16(&Wtm[(n0 + row) * 512 + k0n + g * 8], &Bs[rowb * 64]);
      }
    }
#pragma unroll
    for (int i = 0; i < 4; i++)
#pragma unroll
      for (int j = 0; j < 4; j++)
        acc[i][j] = __builtin_amdgcn_mfma_f32_16x16x32_bf16(a[i], b[j], acc[i][j], 0, 0, 0);
  }

  if (z < 2) {
    u8* O = (z == 0) ? Qo : Ko;
#pragma unroll
    for (int i = 0; i < 4; i++) {
      int rbase = m0 + wr * 64 + i * 16 + quad * 4;
#pragma unroll
      for (int j = 0; j < 4; j++) {
        int col = n0 + wc * 64 + j * 16 + lrow;
        u32 pk01 = cvt_pk_fp8(acc[i][j][0], acc[i][j][1]);
        u32 pk23 = cvt_pk_fp8(acc[i][j][2], acc[i][j][3]);
        O[(rbase + 0) * 512 + col] = (u8)pk01;
        O[(rbase + 1) * 512 + col] = (u8)(pk01 >> 8);
        O[(rbase + 2) * 512 + col] = (u8)pk23;
        O[(rbase + 3) * 512 + col] = (u8)(pk23 >> 8);
      }
    }
  } else {
#pragma unroll
    for (int i = 0; i < 4; i++) {
      int rbase = m0 + wr * 64 + i * 16 + quad * 4;
#pragma unroll
      for (int j = 0; j < 4; j++) {
        int col = n0 + wc * 64 + j * 16 + lrow;
        u32 pk01 = cvt_pk_fp8(acc[i][j][0], acc[i][j][1]);
        u32 pk23 = cvt_pk_fp8(acc[i][j][2], acc[i][j][3]);
        u32 pk = (pk01 & 0xffffu) | (pk23 << 16);
        *(u32*)&Vto8[col * 16384 + rbase] = pk;
      }
    }
  }
}

// ---------------------------------------------------------------------------
// Kernel 3: flash attention partial, all-fp8 MFMA paths.
// QK: mfma 16x16x32 fp8.  PV: mfma 32x32x16 fp8 (P and V quantized e4m3).
//
// NEW (this round): double-buffered K/V LDS + raw s_barrier + COUNTED vmcnt.
//   - Ks8[2]/Vs8[2]: prefetch distance 2 tiles; top-of-loop waits vmcnt(8)
//     (tile it complete, tile it+1 stays in flight across the barrier).
//   - No full vmcnt(0) drain in the main loop (T3+T4 pattern).
//   - s_setprio(1) around both MFMA clusters (T5).
//   - P -> fp8 via v_cvt_pk_fp8_f32 (was ~10-op bit-twiddle per value).
// Hazards:
//   barrier A (after vmcnt wait): tile-it DMAs visible to all waves.
//   lgkmcnt(0)+barrier B: P visible to all; all QK reads of Ks[cur] drained
//     -> safe to issue K(it+2) into Ks[cur] after barrier B.
//   V restage is wave-private (same rows staged & read) -> only needs the
//     wave's own lgkmcnt(0) after its PV fragment reads.
//   P(it+1) writes vs P(it) reads: reads drained at pre-PV lgkmcnt(0),
//     which precedes every wave's arrival at barrier A(it+1).
// LDS: 32K (K dbuf) + 32K (V dbuf) + 2.5K (P) = 68,096 B -> 2 blocks/CU.
// ---------------------------------------------------------------------------
__launch_bounds__(256, 2)
__global__ void attn_partial_kernel(const u8* __restrict__ Q,
                                    const u8* __restrict__ K,
                                    const u8* __restrict__ Vt8,
                                    u16* __restrict__ O0b,
                                    u16* __restrict__ O1b,
                                    float* __restrict__ L) {  // [2][16384]
  const int b = blockIdx.y;
  const int split = blockIdx.z;
  const int q0 = blockIdx.x * 64;
  const int tid = threadIdx.x;
  const int lane = tid & 63, w = tid >> 6;
  const int lrow = lane & 15, quad = lane >> 4;
  const int l31 = lane & 31, half = lane >> 5;

  __shared__ __align__(16) u8 Ks8[2][32 * 512];  // fp8, granule swizzle g^(row&7)
  __shared__ __align__(16) u8 Vs8[2][512 * 32];  // fp8, granule g16^((n>>2)&1)
  __shared__ __align__(16) u8 Pb8[64 * 40];      // fp8 P, row stride 40 B

  const int keybase = b * 4096 + split * 2048;

  // ---- Q fragments: load and force materialization BEFORE any staging DMA
  // (so the compiler's own vmcnt bookkeeping never inserts a drain in-loop).
  const int qtok = b * 4096 + q0 + w * 16 + lrow;
  i64 qf[16];
#pragma unroll
  for (int s = 0; s < 16; s++)
    qf[s] = *(const i64*)&Q[qtok * 512 + s * 32 + quad * 8];
#pragma unroll
  for (int s = 0; s < 16; s++)
    asm volatile("" : "+v"(qf[s]));   // keep live + completed here

  f32x16 Oacc[2][4];
#pragma unroll
  for (int i = 0; i < 2; i++)
#pragma unroll
    for (int j = 0; j < 4; j++)
#pragma unroll
      for (int e = 0; e < 16; e++) Oacc[i][j][e] = 0.f;

  float lsum[4] = {0.f, 0.f, 0.f, 0.f};
  const float scale = 0.044194173824159216f;  // 1/sqrt(512)

  // ---- staging helpers: 4 K-loads + 4 V-loads = 8 vmem ops per tile/wave
  auto stageK = [&](int kk, u8* Kbuf) {
#pragma unroll
    for (int i = 0; i < 4; i++) {
      int row = w * 8 + i * 2 + (lane >> 5);
      int g = (lane & 31) ^ (row & 7);
      gload_lds16(&K[(keybase + kk + row) * 512 + g * 16],
                  &Kbuf[(w * 8 + i * 2) * 512]);
    }
  };
  auto stageV = [&](int kk, u8* Vbuf) {
#pragma unroll
    for (int run = 0; run < 4; run++) {
      int rowb = w * 128 + run * 32;
      int n = rowb + (lane >> 1);
      int g16 = (lane & 1) ^ ((n >> 2) & 1);
      gload_lds16(&Vt8[n * 16384 + keybase + kk + g16 * 16], &Vbuf[rowb * 32]);
    }
  };

  // ---- prologue: tiles 0 and 1 in flight (16 vmem ops outstanding)
  stageK(0, Ks8[0]);  stageV(0, Vs8[0]);
  stageK(32, Ks8[1]); stageV(32, Vs8[1]);

  for (int it = 0; it < 64; ++it) {
    const int cur = it & 1;
    u8* Ksc = Ks8[cur];
    u8* Vsc = Vs8[cur];

    // Tile it complete; tile it+1 (8 newest ops) stays in flight.
    if (it == 63) { asm volatile("s_waitcnt vmcnt(0)" ::: "memory"); }
    else         { asm volatile("s_waitcnt vmcnt(8)" ::: "memory"); }
    __builtin_amdgcn_s_barrier();     // A: tile it staged by all waves

    // ---- QK^T (fp8) : S[16 rows][32 keys] per wave ----
    f32x4 S0 = {0.f, 0.f, 0.f, 0.f}, S1 = {0.f, 0.f, 0.f, 0.f};
    __builtin_amdgcn_s_setprio(1);
#pragma unroll
    for (int s = 0; s < 16; s++) {
      int gs = (2 * s + (quad >> 1)) ^ (lrow & 7);
      int off = gs * 16 + (quad & 1) * 8;
      i64 k0 = *(const i64*)&Ksc[lrow * 512 + off];
      i64 k1 = *(const i64*)&Ksc[(16 + lrow) * 512 + off];
      S0 = __builtin_amdgcn_mfma_f32_16x16x32_fp8_fp8(qf[s], k0, S0, 0, 0, 0);
      S1 = __builtin_amdgcn_mfma_f32_16x16x32_fp8_fp8(qf[s], k1, S1, 0, 0, 0);
    }
    __builtin_amdgcn_s_setprio(0);

    // ---- fixed-max softmax + write P as fp8 (HW packed convert) ----
#pragma unroll
    for (int r = 0; r < 4; r++) {
      float p0 = __expf(S0[r] * scale);
      float p1 = __expf(S1[r] * scale);
      lsum[r] += p0 + p1;
      u32 pk = cvt_pk_fp8(p0, p1);
      int prow = w * 16 + quad * 4 + r;
      Pb8[prow * 40 + lrow] = (u8)pk;
      Pb8[prow * 40 + 16 + lrow] = (u8)(pk >> 8);
    }

    asm volatile("s_waitcnt lgkmcnt(0)" ::: "memory");
    __builtin_amdgcn_s_barrier();     // B: P visible; Ks[cur] fully consumed

    const int kk2 = (it + 2) * 32;
    if (kk2 < 2048) stageK(kk2, Ksc);   // K(it+2) -> just-freed K buffer

    // ---- PV (fp8): hoist fragment reads, drain, restage V, MFMA ----
    i64 af[2][2];
#pragma unroll
    for (int i = 0; i < 2; i++)
#pragma unroll
      for (int kg = 0; kg < 2; kg++)
        af[i][kg] = *(const i64*)&Pb8[(i * 32 + l31) * 40 + kg * 16 + half * 8];

    i64 bv[4][2];
#pragma unroll
    for (int j = 0; j < 4; j++) {
      int n = w * 128 + j * 32 + l31;
      int x = (n >> 2) & 1;
#pragma unroll
      for (int kg = 0; kg < 2; kg++)
        bv[j][kg] = *(const i64*)&Vsc[n * 32 + (kg ^ x) * 16 + half * 8];
    }

    asm volatile("s_waitcnt lgkmcnt(0)" ::: "memory");

    if (kk2 < 2048) stageV(kk2, Vsc);   // V(it+2), wave-private rows

    __builtin_amdgcn_s_setprio(1);
#pragma unroll
    for (int j = 0; j < 4; j++)
#pragma unroll
      for (int i = 0; i < 2; i++) {
        Oacc[i][j] = __builtin_amdgcn_mfma_f32_32x32x16_fp8_fp8(af[i][0], bv[j][0], Oacc[i][j], 0, 0, 0);
        Oacc[i][j] = __builtin_amdgcn_mfma_f32_32x32x16_fp8_fp8(af[i][1], bv[j][1], Oacc[i][j], 0, 0, 0);
      }
    __builtin_amdgcn_s_setprio(0);
  }

  // ---- reduce l across the 16 key-lanes ----
#pragma unroll
  for (int r = 0; r < 4; r++) {
    float s = lsum[r];
    s += __shfl_xor(s, 1); s += __shfl_xor(s, 2);
    s += __shfl_xor(s, 4); s += __shfl_xor(s, 8);
    lsum[r] = s;
  }
  const int tokw = b * 4096 + q0 + w * 16 + quad * 4;
  if (lrow == 0) {
#pragma unroll
    for (int r = 0; r < 4; r++)
      L[split * 16384 + tokw + r] = lsum[r];
  }

  // ---- store unnormalized O partial, bf16 (32x32 C-layout) ----
  u16* Ob = (split == 0) ? O0b : O1b;
  const int tokbase = b * 4096 + q0;
#pragma unroll
  for (int i = 0; i < 2; i++)
#pragma unroll
    for (int j = 0; j < 4; j++) {
      int col = w * 128 + j * 32 + l31;
#pragma unroll
      for (int p = 0; p < 16; p++) {
        int row = i * 32 + (p & 3) + 8 * (p >> 2) + 4 * half;
        Ob[(tokbase + row) * 512 + col] = f2bf(Oacc[i][j][p]);
      }
    }
}

// ---------------------------------------------------------------------------
// Kernel 4: combine splits + residual + LayerNorm.  One wave per token.
// ---------------------------------------------------------------------------
__launch_bounds__(256)
__global__ void combine_ln_kernel(const u16* __restrict__ O0b,
                                  const u16* __restrict__ O1b,
                                  const float* __restrict__ L,
                                  const float* __restrict__ X,
                                  const float* __restrict__ gamma,
                                  const float* __restrict__ beta,
                                  float* __restrict__ Out) {
  const int lane = threadIdx.x & 63;
  const int tok = blockIdx.x * 4 + (threadIdx.x >> 6);
  const float inv_l = 1.f / (L[tok] + L[16384 + tok]);
  const int base = tok * 512 + lane * 8;

  uint4 avec = *(const uint4*)&O0b[base];
  uint4 bvec = *(const uint4*)&O1b[base];
  const u16* ap = (const u16*)&avec;
  const u16* bp = (const u16*)&bvec;
  float4 x0 = *(const float4*)&X[base];
  float4 x1 = *(const float4*)&X[base + 4];
  float xs[8] = {x0.x, x0.y, x0.z, x0.w, x1.x, x1.y, x1.z, x1.w};

  float h[8];
#pragma unroll
  for (int i = 0; i < 8; i++)
    h[i] = (bf2f(ap[i]) + bf2f(bp[i])) * inv_l + xs[i];

  float sum = 0.f, sq = 0.f;
#pragma unroll
  for (int i = 0; i < 8; i++) { sum += h[i]; sq += h[i] * h[i]; }
#pragma unroll
  for (int d = 1; d < 64; d <<= 1) {
    sum += __shfl_xor(sum, d);
    sq  += __shfl_xor(sq, d);
  }
  float mu = sum * (1.f / 512.f);
  float var = sq * (1.f / 512.f) - mu * mu;
  float rstd = rsqrtf(var + LN_EPS);

  float4 g0 = *(const float4*)&gamma[lane * 8];
  float4 g1 = *(const float4*)&gamma[lane * 8 + 4];
  float4 b0 = *(const float4*)&beta[lane * 8];
  float4 b1 = *(const float4*)&beta[lane * 8 + 4];
  float gs[8] = {g0.x, g0.y, g0.z, g0.w, g1.x, g1.y, g1.z, g1.w};
  float bs[8] = {b0.x, b0.y, b0.z, b0.w, b1.x, b1.y, b1.z, b1.w};

  float4 o0, o1;
  float* op = (float*)&o0;
#pragma unroll
  for (int i = 0; i < 4; i++) op[i] = (h[i] - mu) * rstd * gs[i] + bs[i];
  float* op1 = (float*)&o1;
#pragma unroll
  for (int i = 0; i < 4; i++) op1[i] = (h[i + 4] - mu) * rstd * gs[i + 4] + bs[i + 4];
  *(float4*)&Out[base] = o0;
  *(float4*)&Out[base + 4] = o1;
}

// ---------------------------------------------------------------------------
extern "C" void kernel_launch(void* const* d_in, const int* in_sizes, int n_in,
                              void* d_out, int out_size, void* d_ws, size_t ws_size,
                              hipStream_t stream) {
  const float* x = (const float*)d_in[0];
  const float* Wq = (const float*)d_in[1];
  const float* Wk = (const float*)d_in[2];
  const float* Wv = (const float*)d_in[3];
  const float* gamma = (const float*)d_in[4];
  const float* beta = (const float*)d_in[5];

  char* ws = (char*)d_ws;
  u8*  Qws   = (u8*)(ws);                     // 8 MB fp8
  u8*  Kws   = (u8*)(ws + 8388608);           // 8 MB fp8
  u8*  Vt8ws = (u8*)(ws + 16777216);          // 8 MB fp8, [512][16384]
  u16* Wtws  = (u16*)(ws + 25165824);         // 1.5 MB bf16
  u16* Xbws  = (u16*)(ws + 26738688);         // 16 MB bf16 (dead after GEMM)
  u16* O0bws = (u16*)(ws + 26738688);         // 16 MB bf16 (aliases Xb - safe,
                                              //   attn writes after gemm reads)
  u16* O1bws = (u16*)(ws + 43515904);         // 16 MB bf16
  float* Lws = (float*)(ws + 60293120);       // 128 KB [2][16384]

  hipLaunchKernelGGL(xcast_kernel, dim3(4096), dim3(256), 0, stream, x, Xbws);
  hipLaunchKernelGGL(transpose_w_kernel, dim3(1024, 3), dim3(256), 0, stream,
                     Wq, Wk, Wv, Wtws);
  hipLaunchKernelGGL(qkv_gemm_kernel, dim3(512, 3), dim3(256), 0, stream,
                     Xbws, Wtws, Qws, Kws, Vt8ws);
  hipLaunchKernelGGL(attn_partial_kernel, dim3(64, 4, 2), dim3(256), 0, stream,
                     Qws, Kws, Vt8ws, O0bws, O1bws, Lws);
  hipLaunchKernelGGL(combine_ln_kernel, dim3(4096), dim3(256), 0, stream,
                     O0bws, O1bws, Lws, x, gamma, beta, (float*)d_out);
}